// Round 20
// baseline (115.104 us; speedup 1.0000x reference)
//
#include <hip/hip_runtime.h>
#include <math.h>

// SOM2dLayer forward: BMU indices + quantization error.
// X[4096,64] f32, W[65536,64] f32 -> out f32: [B*2] (y,x) then [B] qe.
//
// acc'(row,n) = bf16dot(x,w) + w2c[n], w2c = -0.5*sum(w^2); s = -2*acc'.
// min_n s  <=>  max_n acc'.
//   k_prep:    fp32 -> bf16 copies (W and X) + exact w2c
//   k_screen0: r17 screen (depth-1-pair register prefetch, rg=8, barrier-
//              free, direct-global B) + row-major pm[row][sub] (r19) with
//              r20 fix: the wave's two subs are CONSECUTIVE (nr*2, nr*2+1),
//              so defer ch=0's folded pm values in registers and emit one
//              aligned float2 per (lane,rg) at ch=1 -- halves pm store
//              transactions (r19's 4B scatter amplified WRITE 37->64MB,
//              costing the screen ~4us).
//   k_rescore: coalesced pv gather (pm[row][sub]); thr = max(pm)-MARG;
//              qualifying coarse subs -> fine subs -> exact fp32 rescore
//              (16 n each); argmin, first-index tie-break; qe.
// Round-up bf16 pmf is conservative -> candidate superset, no false
// negatives. No atomics, no barriers -> deterministic.

typedef short  bf16x8 __attribute__((ext_vector_type(8)));
typedef float  f32x4  __attribute__((ext_vector_type(4)));
typedef float  f32x2  __attribute__((ext_vector_type(2)));
typedef unsigned short u16;

constexpr int D     = 64;
constexpr int NW    = 65536;
constexpr int B     = 4096;
constexpr int NSUB  = 256;             // coarse subs: 256 contiguous n each
constexpr int NFINE = NW / 16;         // 4096 fine subs (16 n each)
constexpr float MARG_HALF = 0.15f;     // bf16 screen margin (acc' scale)

constexpr int NRANGE = 128;            // n-ranges of 512 n (one per wave)
constexpr int RBKB   = 8;              // row-super-blocks (4 waves x 128 rows)

__device__ inline u16 bf16u(float f) {
    union { float f; unsigned u; } v; v.f = f;
    unsigned b = v.u;
    b += 0x7fffu + ((b >> 16) & 1u);   // RNE, finite inputs only
    return (u16)(b >> 16);
}

__device__ inline u16 bf16up(float f) {   // round toward +inf (conservative max)
    union { float f; unsigned u; } v; v.f = f;
    unsigned h = v.u >> 16;
    if ((v.u & 0xFFFFu) && !(v.u >> 31)) h += 1;
    return (u16)h;
}

// ---- prep: W,X -> bf16 + w2c (fused, one launch) --------------------------
__global__ __launch_bounds__(256) void k_prep(const float* __restrict__ w,
                                              const float* __restrict__ x,
                                              u16* __restrict__ whi,
                                              u16* __restrict__ xhi,
                                              float* __restrict__ w2c) {
    const int idx = blockIdx.x * 256 + threadIdx.x;
    if (idx < NW) {
        const float4* wr = reinterpret_cast<const float4*>(w + (size_t)idx * D);
        u16* orow = whi + (size_t)idx * D;
        float a0 = 0.f, a1 = 0.f, a2 = 0.f, a3 = 0.f;
#pragma unroll
        for (int h = 0; h < 8; ++h) {
            float4 v0 = wr[2 * h], v1 = wr[2 * h + 1];
            a0 = fmaf(v0.x, v0.x, a0); a1 = fmaf(v0.y, v0.y, a1);
            a2 = fmaf(v0.z, v0.z, a2); a3 = fmaf(v0.w, v0.w, a3);
            a0 = fmaf(v1.x, v1.x, a0); a1 = fmaf(v1.y, v1.y, a1);
            a2 = fmaf(v1.z, v1.z, a2); a3 = fmaf(v1.w, v1.w, a3);
            bf16x8 o = {(short)bf16u(v0.x), (short)bf16u(v0.y),
                        (short)bf16u(v0.z), (short)bf16u(v0.w),
                        (short)bf16u(v1.x), (short)bf16u(v1.y),
                        (short)bf16u(v1.z), (short)bf16u(v1.w)};
            *reinterpret_cast<bf16x8*>(orow + 8 * h) = o;
        }
        w2c[idx] = -0.5f * ((a0 + a1) + (a2 + a3));
    } else {
        const int r = idx - NW;
        const float4* xr = reinterpret_cast<const float4*>(x + (size_t)r * D);
        u16* orow = xhi + (size_t)r * D;
#pragma unroll
        for (int h = 0; h < 8; ++h) {
            float4 v0 = xr[2 * h], v1 = xr[2 * h + 1];
            bf16x8 o = {(short)bf16u(v0.x), (short)bf16u(v0.y),
                        (short)bf16u(v0.z), (short)bf16u(v0.w),
                        (short)bf16u(v1.x), (short)bf16u(v1.y),
                        (short)bf16u(v1.z), (short)bf16u(v1.w)};
            *reinterpret_cast<bf16x8*>(orow + 8 * h) = o;
        }
    }
}

// ---- MFMA screen: rg=8, barrier-free, depth-1-pair register prefetch ------
// Block: 256 thr = 4 independent waves. nr = bid & 127; rbk = (bid>>7)*4+wv.
// Wave: rows [rbk*128, +128), n [nr*512, +512) = 16 tile-pairs (32 n each),
// 2 chunks of 256 n. XCD: bid%8 == nr%8.
// sub = nr*2 + ch (contiguous). fine (sub,col): n = sub*256 + j*16 + col.
// pm[row][sub] f32 (row-major, float2 per wave at ch=1);
// pmf[(sub*32+row>>7)*2048+(row&127)*16+col] u16 block-linear.
template <int WRITE_FINE>
__global__ __launch_bounds__(256, 2) void k_screen0(
        const u16* __restrict__ whi, const u16* __restrict__ xhi,
        const float* __restrict__ w2c, float* __restrict__ pm,
        u16* __restrict__ pmf) {
    __shared__ __align__(16) u16 fsh[4][2048];   // per-wave flush staging
    const int bid  = blockIdx.x;
    const int nr   = bid & (NRANGE - 1);
    const int tid  = threadIdx.x;
    const int wv   = tid >> 6;
    const int lane = tid & 63;
    const int col  = lane & 15;
    const int kg   = lane >> 4;
    const int rbk  = (bid >> 7) * 4 + wv;
    const int row0 = rbk * 128;
    const int W0   = nr * 512;

    // A fragments (x rows), resident whole kernel: 8 rg x 2 k-halves.
    bf16x8 a[8][2];
#pragma unroll
    for (int rg = 0; rg < 8; ++rg)
#pragma unroll
        for (int h = 0; h < 2; ++h)
            a[rg][h] = *reinterpret_cast<const bf16x8*>(
                xhi + (size_t)(row0 + rg * 16 + col) * D + h * 32 + kg * 8);

    float mx[8][4];
#pragma unroll
    for (int rg = 0; rg < 8; ++rg)
#pragma unroll
        for (int r = 0; r < 4; ++r) mx[rg][r] = -3.4e38f;

    float pmk[8];   // ch=0's folded pm values (valid in col<4 lanes)

    // pair-load into named registers (depth-1 prefetch sets)
    bf16x8 cb00, cb01, cb10, cb11, nb00, nb01, nb10, nb11;
    float  cc0, cc1, nc0, nc1;
    auto LDP = [&](int pp, bf16x8& b00, bf16x8& b01, bf16x8& b10, bf16x8& b11,
                   float& c0, float& c1) {
        const int n0 = W0 + pp * 32 + col;
        const int n1 = n0 + 16;
        const u16* p0 = whi + (size_t)n0 * D + kg * 8;
        const u16* p1 = whi + (size_t)n1 * D + kg * 8;
        b00 = *reinterpret_cast<const bf16x8*>(p0);
        b01 = *reinterpret_cast<const bf16x8*>(p0 + 32);
        b10 = *reinterpret_cast<const bf16x8*>(p1);
        b11 = *reinterpret_cast<const bf16x8*>(p1 + 32);
        c0 = w2c[n0];
        c1 = w2c[n1];
    };

    LDP(0, cb00, cb01, cb10, cb11, cc0, cc1);

    for (int ch = 0; ch < 2; ++ch) {
        for (int mp = 0; mp < 8; ++mp) {
            const int pp = ch * 8 + mp;
            // issue NEXT pair's loads before current pair's compute
            if (pp + 1 < 16)
                LDP(pp + 1, nb00, nb01, nb10, nb11, nc0, nc1);

            const f32x4 cq0 = {cc0, cc0, cc0, cc0};
            const f32x4 cq1 = {cc1, cc1, cc1, cc1};
#pragma unroll
            for (int rg = 0; rg < 8; ++rg) {
                f32x4 acc = __builtin_amdgcn_mfma_f32_16x16x32_bf16(a[rg][0], cb00, cq0, 0, 0, 0);
                acc = __builtin_amdgcn_mfma_f32_16x16x32_bf16(a[rg][1], cb01, acc, 0, 0, 0);
                mx[rg][0] = fmaxf(mx[rg][0], acc[0]);
                mx[rg][1] = fmaxf(mx[rg][1], acc[1]);
                mx[rg][2] = fmaxf(mx[rg][2], acc[2]);
                mx[rg][3] = fmaxf(mx[rg][3], acc[3]);
            }
#pragma unroll
            for (int rg = 0; rg < 8; ++rg) {
                f32x4 acc = __builtin_amdgcn_mfma_f32_16x16x32_bf16(a[rg][0], cb10, cq1, 0, 0, 0);
                acc = __builtin_amdgcn_mfma_f32_16x16x32_bf16(a[rg][1], cb11, acc, 0, 0, 0);
                mx[rg][0] = fmaxf(mx[rg][0], acc[0]);
                mx[rg][1] = fmaxf(mx[rg][1], acc[1]);
                mx[rg][2] = fmaxf(mx[rg][2], acc[2]);
                mx[rg][3] = fmaxf(mx[rg][3], acc[3]);
            }
            cb00 = nb00; cb01 = nb01; cb10 = nb10; cb11 = nb11;
            cc0 = nc0;   cc1 = nc1;
        }

        // ---- chunk flush (2 per kernel, wave-private, no barriers) ----
        const int sub = nr * 2 + ch;

        if (WRITE_FINE) {   // transpose deposit -> coalesced writeout
#pragma unroll
            for (int rg = 0; rg < 8; ++rg)
#pragma unroll
                for (int r = 0; r < 4; ++r)
                    fsh[wv][(rg * 16 + kg * 4 + r) * 16 + col] = bf16up(mx[rg][r]);
        }

#pragma unroll
        for (int rg = 0; rg < 8; ++rg) {
            float v0 = mx[rg][0], v1 = mx[rg][1], v2 = mx[rg][2], v3 = mx[rg][3];
#pragma unroll
            for (int sh = 1; sh < 16; sh <<= 1) {
                v0 = fmaxf(v0, __shfl_xor(v0, sh, 64));
                v1 = fmaxf(v1, __shfl_xor(v1, sh, 64));
                v2 = fmaxf(v2, __shfl_xor(v2, sh, 64));
                v3 = fmaxf(v3, __shfl_xor(v3, sh, 64));
            }
            float vv = v0;
            vv = (col == 1) ? v1 : vv;
            vv = (col == 2) ? v2 : vv;
            vv = (col == 3) ? v3 : vv;
            if (ch == 0) {
                pmk[rg] = vv;            // defer: write both subs as float2
            } else if (col < 4) {
                f32x2 pr = {pmk[rg], vv};
                *reinterpret_cast<f32x2*>(
                    &pm[(size_t)(row0 + rg * 16 + kg * 4 + col) * NSUB + nr * 2]) = pr;
            }
            mx[rg][0] = -3.4e38f; mx[rg][1] = -3.4e38f;
            mx[rg][2] = -3.4e38f; mx[rg][3] = -3.4e38f;
        }

        if (WRITE_FINE) {   // 4x float4 per lane, fully coalesced
            const char* src = reinterpret_cast<const char*>(&fsh[wv][0]);
            char* dst = (char*)pmf + ((size_t)sub * 32 + rbk) * 4096;
#pragma unroll
            for (int i = 0; i < 4; ++i)
                *reinterpret_cast<float4*>(dst + i * 1024 + lane * 16) =
                    *reinterpret_cast<const float4*>(src + i * 1024 + lane * 16);
        }
    }
}

// ---- exact fp32 rescore + output (one wave per row) -----------------------
// sub -> base = sub*256; fine (sub,c): j = 0..15 -> n = base + j*16 + c
template <int FINE>
__global__ __launch_bounds__(256) void k_rescore(
        const float* __restrict__ x, const float* __restrict__ w,
        const float* __restrict__ w2c, const float* __restrict__ pm,
        const u16* __restrict__ pmf, float* __restrict__ out) {
    const int wv   = threadIdx.x >> 6;
    const int lane = threadIdx.x & 63;
    const int row  = blockIdx.x * 4 + wv;
    const int rbk2 = row >> 7;
    const int rl   = row & 127;

    float pv[4];
#pragma unroll
    for (int it = 0; it < 4; ++it)
        pv[it] = pm[(size_t)row * NSUB + it * 64 + lane];   // coalesced
    float gm = fmaxf(fmaxf(pv[0], pv[1]), fmaxf(pv[2], pv[3]));
#pragma unroll
    for (int s = 1; s < 64; s <<= 1) gm = fmaxf(gm, __shfl_xor(gm, s, 64));
    const float thr = gm - MARG_HALF;

    const float4* xr = reinterpret_cast<const float4*>(x + (size_t)row * D);
    float4 xq[16];
#pragma unroll
    for (int q = 0; q < 16; ++q) xq[q] = xr[q];

    float bestv = 3.4e38f;
    int   besti = 0x7fffffff;

#pragma unroll
    for (int it = 0; it < 4; ++it) {
        unsigned long long bm = __ballot(pv[it] >= thr);
        while (bm) {
            int sb = __ffsll(bm) - 1;
            bm &= bm - 1;
            int sub  = it * 64 + sb;
            int base = sub * 256;

            if (FINE) {
                // 16 fine bf16 (round-up) maxes, 32B coalesced
                float fv = -3.4e38f;
                if (lane < 16) {
                    union { unsigned u; float f; } c;
                    c.u = (unsigned)pmf[((size_t)sub * 32 + rbk2) * 2048
                                        + rl * 16 + lane] << 16;
                    fv = c.f;
                }
                unsigned long long fm = __ballot(fv >= thr);   // bits 0..15
                while (fm) {
                    int colq = __ffsll(fm) - 1;
                    fm &= fm - 1;
                    // fine sub n-set: base + j*16 + colq, j = 0..15
                    int j = lane & 15, q = lane >> 4;
                    int n = base + j * 16 + colq;
                    const float4* wr = reinterpret_cast<const float4*>(w + (size_t)n * D);
                    float d0 = 0.f, d1 = 0.f, d2 = 0.f, d3 = 0.f;
#pragma unroll
                    for (int k = 0; k < 4; ++k) {
                        float4 wq = wr[q * 4 + k];
                        float4 xv = xq[q * 4 + k];
                        d0 = fmaf(xv.x, wq.x, d0); d1 = fmaf(xv.y, wq.y, d1);
                        d2 = fmaf(xv.z, wq.z, d2); d3 = fmaf(xv.w, wq.w, d3);
                    }
                    float d = (d0 + d1) + (d2 + d3);
                    d += __shfl_xor(d, 16, 64);
                    d += __shfl_xor(d, 32, 64);      // all 4 copies hold full dot
                    float val = -2.f * (d + w2c[n]);  // == w2 - 2*x.w exact fp32
                    if (val < bestv || (val == bestv && n < besti)) { bestv = val; besti = n; }
                }
            } else {
#pragma unroll
                for (int p4 = 0; p4 < 4; ++p4) {
                    int n = base + p4 * 64 + lane;
                    const float4* wr = reinterpret_cast<const float4*>(w + (size_t)n * D);
                    float d0 = 0.f, d1 = 0.f, d2 = 0.f, d3 = 0.f;
#pragma unroll
                    for (int q = 0; q < 16; ++q) {
                        float4 wq = wr[q];
                        d0 = fmaf(xq[q].x, wq.x, d0);
                        d1 = fmaf(xq[q].y, wq.y, d1);
                        d2 = fmaf(xq[q].z, wq.z, d2);
                        d3 = fmaf(xq[q].w, wq.w, d3);
                    }
                    float dot = (d0 + d1) + (d2 + d3);
                    float val = -2.f * (dot + w2c[n]);
                    if (val < bestv || (val == bestv && n < besti)) { bestv = val; besti = n; }
                }
            }
        }
    }
#pragma unroll
    for (int s = 1; s < 64; s <<= 1) {
        float ov = __shfl_xor(bestv, s, 64);
        int   oi = __shfl_xor(besti, s, 64);
        if (ov < bestv || (ov == bestv && oi < besti)) { bestv = ov; besti = oi; }
    }
    if (lane == 0) {
        float a0 = 0.f, a1 = 0.f, a2 = 0.f, a3 = 0.f;
#pragma unroll
        for (int q = 0; q < 16; ++q) {
            a0 = fmaf(xq[q].x, xq[q].x, a0);
            a1 = fmaf(xq[q].y, xq[q].y, a1);
            a2 = fmaf(xq[q].z, xq[q].z, a2);
            a3 = fmaf(xq[q].w, xq[q].w, a3);
        }
        float x2 = (a0 + a1) + (a2 + a3);
        float d2f = x2 + bestv;
        if (d2f < 0.f) d2f = 0.f;
        out[row * 2 + 0] = (float)(besti >> 8);    // bmu_y
        out[row * 2 + 1] = (float)(besti & 255);   // bmu_x
        out[2 * B + row] = sqrtf(d2f);
    }
}

// ---- fallback (round-3 proven path, ~1.3 MB ws) ---------------------------
__global__ __launch_bounds__(256) void fb_w2(const float* __restrict__ w,
                                             float* __restrict__ w2) {
    int n = blockIdx.x * 256 + threadIdx.x;
    const float4* wr = reinterpret_cast<const float4*>(w + (size_t)n * D);
    float a0 = 0.f, a1 = 0.f, a2 = 0.f, a3 = 0.f;
#pragma unroll
    for (int q = 0; q < 16; ++q) {
        float4 v = wr[q];
        a0 = fmaf(v.x, v.x, a0); a1 = fmaf(v.y, v.y, a1);
        a2 = fmaf(v.z, v.z, a2); a3 = fmaf(v.w, v.w, a3);
    }
    w2[n] = (a0 + a1) + (a2 + a3);
}

__global__ __launch_bounds__(256) void fb_main(const float* __restrict__ x,
                                               const float* __restrict__ w,
                                               const float* __restrict__ w2,
                                               float* __restrict__ ps,
                                               int* __restrict__ pi) {
    constexpr int NSTRIP = NW / 32;
    const int rb    = blockIdx.x & 15;
    const int strip = blockIdx.x >> 4;
    const int row   = rb * 256 + threadIdx.x;
    float xr[D];
    const float4* xrow = reinterpret_cast<const float4*>(x + (size_t)row * D);
#pragma unroll
    for (int q = 0; q < 16; ++q) {
        float4 v = xrow[q];
        xr[q * 4 + 0] = v.x; xr[q * 4 + 1] = v.y;
        xr[q * 4 + 2] = v.z; xr[q * 4 + 3] = v.w;
    }
    float best = 3.4e38f; int bidx = 0;
    const int n0 = strip * NSTRIP, n1 = n0 + NSTRIP;
    for (int n = n0; n < n1; ++n) {
        const float* wr = w + (size_t)n * D;
        float a0 = 0.f, a1 = 0.f, a2 = 0.f, a3 = 0.f;
#pragma unroll
        for (int d = 0; d < D; d += 4) {
            a0 = fmaf(xr[d + 0], wr[d + 0], a0);
            a1 = fmaf(xr[d + 1], wr[d + 1], a1);
            a2 = fmaf(xr[d + 2], wr[d + 2], a2);
            a3 = fmaf(xr[d + 3], wr[d + 3], a3);
        }
        float s = fmaf(-2.f, (a0 + a1) + (a2 + a3), w2[n]);
        if (s < best) { best = s; bidx = n; }
    }
    ps[(size_t)strip * B + row] = best;
    pi[(size_t)strip * B + row] = bidx;
}

__global__ __launch_bounds__(256) void fb_merge(const float* __restrict__ x,
                                                const float* __restrict__ ps,
                                                const int* __restrict__ pi,
                                                float* __restrict__ out) {
    int row = blockIdx.x * 256 + threadIdx.x;
    float bs = 3.5e38f; int bi = 0;
    for (int t = 0; t < 32; ++t) {
        float s = ps[(size_t)t * B + row];
        int   i = pi[(size_t)t * B + row];
        if (s < bs || (s == bs && i < bi)) { bs = s; bi = i; }
    }
    const float4* xrow = reinterpret_cast<const float4*>(x + (size_t)row * D);
    float a0 = 0.f, a1 = 0.f, a2 = 0.f, a3 = 0.f;
#pragma unroll
    for (int q = 0; q < 16; ++q) {
        float4 v = xrow[q];
        a0 = fmaf(v.x, v.x, a0); a1 = fmaf(v.y, v.y, a1);
        a2 = fmaf(v.z, v.z, a2); a3 = fmaf(v.w, v.w, a3);
    }
    float x2 = (a0 + a1) + (a2 + a3);
    float d2 = x2 + bs;
    if (d2 < 0.f) d2 = 0.f;
    out[row * 2 + 0] = (float)(bi >> 8);
    out[row * 2 + 1] = (float)(bi & 255);
    out[2 * B + row] = sqrtf(d2);
}

// ---------------------------------------------------------------------------
extern "C" void kernel_launch(void* const* d_in, const int* in_sizes, int n_in,
                              void* d_out, int out_size, void* d_ws, size_t ws_size,
                              hipStream_t stream) {
    const float* x = (const float*)d_in[0];   // [B, D]
    const float* w = (const float*)d_in[1];   // [NW, D]
    float* out = (float*)d_out;

    const size_t whi_sz = (size_t)NW * D * 2;        // 8 MB
    const size_t xhi_sz = (size_t)B * D * 2;         // 512 KB
    const size_t w2c_sz = (size_t)NW * 4;            // 256 KB
    const size_t pm_sz  = (size_t)B * NSUB * 4;      // 4 MB
    const size_t pmf_sz = (size_t)NFINE * B * 2;     // 33.5 MB
    const size_t need_c = whi_sz + xhi_sz + w2c_sz + pm_sz;
    const size_t need_f = need_c + pmf_sz;

    if (ws_size >= need_c) {
        char* p = (char*)d_ws;
        u16*   whi = (u16*)p;   p += whi_sz;
        u16*   xhi = (u16*)p;   p += xhi_sz;
        float* w2c = (float*)p; p += w2c_sz;
        float* pm  = (float*)p; p += pm_sz;
        u16*   pmf = (u16*)p;

        k_prep<<<(NW + B) / 256, 256, 0, stream>>>(w, x, whi, xhi, w2c);
        if (ws_size >= need_f) {
            k_screen0<1><<<NRANGE * RBKB, 256, 0, stream>>>(whi, xhi, w2c, pm, pmf);
            k_rescore<1><<<B / 4, 256, 0, stream>>>(x, w, w2c, pm, pmf, out);
        } else {
            k_screen0<0><<<NRANGE * RBKB, 256, 0, stream>>>(whi, xhi, w2c, pm, pmf);
            k_rescore<0><<<B / 4, 256, 0, stream>>>(x, w, w2c, pm, pmf, out);
        }
    } else {
        float* w2 = (float*)d_ws;
        float* ps = w2 + NW;
        int*   pi = (int*)(ps + (size_t)32 * B);
        fb_w2<<<NW / 256, 256, 0, stream>>>(w, w2);
        fb_main<<<16 * 32, 256, 0, stream>>>(x, w, w2, ps, pi);
        fb_merge<<<B / 256, 256, 0, stream>>>(x, ps, pi, out);
    }
}

// Round 21
// 111.555 us; speedup vs baseline: 1.0318x; 1.0318x over previous
//
#include <hip/hip_runtime.h>
#include <math.h>

// SOM2dLayer forward: BMU indices + quantization error.
// X[4096,64] f32, W[65536,64] f32 -> out f32: [B*2] (y,x) then [B] qe.
//
// acc'(row,n) = bf16dot(x,w) + w2c[n], w2c = -0.5*sum(w^2); s = -2*acc'.
// min_n s  <=>  max_n acc'.
//   k_prep:    r21 change -- SPLIT-ROW prep (2 threads/row, shfl-combined
//              w2 partials): old prep was 272 blocks = 1 wave/SIMD,
//              latency-bound. Now 544 blocks, half-row chains.
//   k_screen0: r20 screen unchanged (depth-1-pair register prefetch, rg=8,
//              barrier-free, direct-global B, float2 pm writes).
//   k_rescore: unchanged (coalesced pv gather, fine bf16 localization,
//              exact fp32 rescore, first-index tie-break).
// Round-up bf16 pmf is conservative -> candidate superset, no false
// negatives. No atomics, no barriers -> deterministic.

typedef short  bf16x8 __attribute__((ext_vector_type(8)));
typedef float  f32x4  __attribute__((ext_vector_type(4)));
typedef float  f32x2  __attribute__((ext_vector_type(2)));
typedef unsigned short u16;

constexpr int D     = 64;
constexpr int NW    = 65536;
constexpr int B     = 4096;
constexpr int NSUB  = 256;             // coarse subs: 256 contiguous n each
constexpr int NFINE = NW / 16;         // 4096 fine subs (16 n each)
constexpr float MARG_HALF = 0.15f;     // bf16 screen margin (acc' scale)

constexpr int NRANGE = 128;            // n-ranges of 512 n (one per wave)
constexpr int RBKB   = 8;              // row-super-blocks (4 waves x 128 rows)

__device__ inline u16 bf16u(float f) {
    union { float f; unsigned u; } v; v.f = f;
    unsigned b = v.u;
    b += 0x7fffu + ((b >> 16) & 1u);   // RNE, finite inputs only
    return (u16)(b >> 16);
}

__device__ inline u16 bf16up(float f) {   // round toward +inf (conservative max)
    union { float f; unsigned u; } v; v.f = f;
    unsigned h = v.u >> 16;
    if ((v.u & 0xFFFFu) && !(v.u >> 31)) h += 1;
    return (u16)h;
}

// ---- prep: W,X -> bf16 + w2c (split-row: 2 threads per row) ---------------
// Threads [0, 2*NW): W rows. Threads [2*NW, 2*NW+2*B): X rows.
// Thread t: row = t>>1, half = t&1 (elements half*32 .. half*32+32).
__global__ __launch_bounds__(256) void k_prep(const float* __restrict__ w,
                                              const float* __restrict__ x,
                                              u16* __restrict__ whi,
                                              u16* __restrict__ xhi,
                                              float* __restrict__ w2c) {
    const int t = blockIdx.x * 256 + threadIdx.x;
    if (t < 2 * NW) {
        const int row  = t >> 1;
        const int half = t & 1;
        const float4* wr = reinterpret_cast<const float4*>(
            w + (size_t)row * D + half * 32);
        u16* orow = whi + (size_t)row * D + half * 32;
        float a0 = 0.f, a1 = 0.f, a2 = 0.f, a3 = 0.f;
#pragma unroll
        for (int h = 0; h < 4; ++h) {
            float4 v0 = wr[2 * h], v1 = wr[2 * h + 1];
            a0 = fmaf(v0.x, v0.x, a0); a1 = fmaf(v0.y, v0.y, a1);
            a2 = fmaf(v0.z, v0.z, a2); a3 = fmaf(v0.w, v0.w, a3);
            a0 = fmaf(v1.x, v1.x, a0); a1 = fmaf(v1.y, v1.y, a1);
            a2 = fmaf(v1.z, v1.z, a2); a3 = fmaf(v1.w, v1.w, a3);
            bf16x8 o = {(short)bf16u(v0.x), (short)bf16u(v0.y),
                        (short)bf16u(v0.z), (short)bf16u(v0.w),
                        (short)bf16u(v1.x), (short)bf16u(v1.y),
                        (short)bf16u(v1.z), (short)bf16u(v1.w)};
            *reinterpret_cast<bf16x8*>(orow + 8 * h) = o;
        }
        float p = (a0 + a1) + (a2 + a3);
        p += __shfl_xor(p, 1, 64);        // combine the two halves
        if (half == 0) w2c[row] = -0.5f * p;
    } else {
        const int t2   = t - 2 * NW;
        const int row  = t2 >> 1;
        const int half = t2 & 1;
        const float4* xr = reinterpret_cast<const float4*>(
            x + (size_t)row * D + half * 32);
        u16* orow = xhi + (size_t)row * D + half * 32;
#pragma unroll
        for (int h = 0; h < 4; ++h) {
            float4 v0 = xr[2 * h], v1 = xr[2 * h + 1];
            bf16x8 o = {(short)bf16u(v0.x), (short)bf16u(v0.y),
                        (short)bf16u(v0.z), (short)bf16u(v0.w),
                        (short)bf16u(v1.x), (short)bf16u(v1.y),
                        (short)bf16u(v1.z), (short)bf16u(v1.w)};
            *reinterpret_cast<bf16x8*>(orow + 8 * h) = o;
        }
    }
}

// ---- MFMA screen: rg=8, barrier-free, depth-1-pair register prefetch ------
// Block: 256 thr = 4 independent waves. nr = bid & 127; rbk = (bid>>7)*4+wv.
// Wave: rows [rbk*128, +128), n [nr*512, +512) = 16 tile-pairs (32 n each),
// 2 chunks of 256 n. XCD: bid%8 == nr%8.
// sub = nr*2 + ch (contiguous). fine (sub,col): n = sub*256 + j*16 + col.
// pm[row][sub] f32 (row-major, float2 per wave at ch=1);
// pmf[(sub*32+row>>7)*2048+(row&127)*16+col] u16 block-linear.
template <int WRITE_FINE>
__global__ __launch_bounds__(256, 2) void k_screen0(
        const u16* __restrict__ whi, const u16* __restrict__ xhi,
        const float* __restrict__ w2c, float* __restrict__ pm,
        u16* __restrict__ pmf) {
    __shared__ __align__(16) u16 fsh[4][2048];   // per-wave flush staging
    const int bid  = blockIdx.x;
    const int nr   = bid & (NRANGE - 1);
    const int tid  = threadIdx.x;
    const int wv   = tid >> 6;
    const int lane = tid & 63;
    const int col  = lane & 15;
    const int kg   = lane >> 4;
    const int rbk  = (bid >> 7) * 4 + wv;
    const int row0 = rbk * 128;
    const int W0   = nr * 512;

    // A fragments (x rows), resident whole kernel: 8 rg x 2 k-halves.
    bf16x8 a[8][2];
#pragma unroll
    for (int rg = 0; rg < 8; ++rg)
#pragma unroll
        for (int h = 0; h < 2; ++h)
            a[rg][h] = *reinterpret_cast<const bf16x8*>(
                xhi + (size_t)(row0 + rg * 16 + col) * D + h * 32 + kg * 8);

    float mx[8][4];
#pragma unroll
    for (int rg = 0; rg < 8; ++rg)
#pragma unroll
        for (int r = 0; r < 4; ++r) mx[rg][r] = -3.4e38f;

    float pmk[8];   // ch=0's folded pm values (valid in col<4 lanes)

    // pair-load into named registers (depth-1 prefetch sets)
    bf16x8 cb00, cb01, cb10, cb11, nb00, nb01, nb10, nb11;
    float  cc0, cc1, nc0, nc1;
    auto LDP = [&](int pp, bf16x8& b00, bf16x8& b01, bf16x8& b10, bf16x8& b11,
                   float& c0, float& c1) {
        const int n0 = W0 + pp * 32 + col;
        const int n1 = n0 + 16;
        const u16* p0 = whi + (size_t)n0 * D + kg * 8;
        const u16* p1 = whi + (size_t)n1 * D + kg * 8;
        b00 = *reinterpret_cast<const bf16x8*>(p0);
        b01 = *reinterpret_cast<const bf16x8*>(p0 + 32);
        b10 = *reinterpret_cast<const bf16x8*>(p1);
        b11 = *reinterpret_cast<const bf16x8*>(p1 + 32);
        c0 = w2c[n0];
        c1 = w2c[n1];
    };

    LDP(0, cb00, cb01, cb10, cb11, cc0, cc1);

    for (int ch = 0; ch < 2; ++ch) {
        for (int mp = 0; mp < 8; ++mp) {
            const int pp = ch * 8 + mp;
            // issue NEXT pair's loads before current pair's compute
            if (pp + 1 < 16)
                LDP(pp + 1, nb00, nb01, nb10, nb11, nc0, nc1);

            const f32x4 cq0 = {cc0, cc0, cc0, cc0};
            const f32x4 cq1 = {cc1, cc1, cc1, cc1};
#pragma unroll
            for (int rg = 0; rg < 8; ++rg) {
                f32x4 acc = __builtin_amdgcn_mfma_f32_16x16x32_bf16(a[rg][0], cb00, cq0, 0, 0, 0);
                acc = __builtin_amdgcn_mfma_f32_16x16x32_bf16(a[rg][1], cb01, acc, 0, 0, 0);
                mx[rg][0] = fmaxf(mx[rg][0], acc[0]);
                mx[rg][1] = fmaxf(mx[rg][1], acc[1]);
                mx[rg][2] = fmaxf(mx[rg][2], acc[2]);
                mx[rg][3] = fmaxf(mx[rg][3], acc[3]);
            }
#pragma unroll
            for (int rg = 0; rg < 8; ++rg) {
                f32x4 acc = __builtin_amdgcn_mfma_f32_16x16x32_bf16(a[rg][0], cb10, cq1, 0, 0, 0);
                acc = __builtin_amdgcn_mfma_f32_16x16x32_bf16(a[rg][1], cb11, acc, 0, 0, 0);
                mx[rg][0] = fmaxf(mx[rg][0], acc[0]);
                mx[rg][1] = fmaxf(mx[rg][1], acc[1]);
                mx[rg][2] = fmaxf(mx[rg][2], acc[2]);
                mx[rg][3] = fmaxf(mx[rg][3], acc[3]);
            }
            cb00 = nb00; cb01 = nb01; cb10 = nb10; cb11 = nb11;
            cc0 = nc0;   cc1 = nc1;
        }

        // ---- chunk flush (2 per kernel, wave-private, no barriers) ----
        const int sub = nr * 2 + ch;

        if (WRITE_FINE) {   // transpose deposit -> coalesced writeout
#pragma unroll
            for (int rg = 0; rg < 8; ++rg)
#pragma unroll
                for (int r = 0; r < 4; ++r)
                    fsh[wv][(rg * 16 + kg * 4 + r) * 16 + col] = bf16up(mx[rg][r]);
        }

#pragma unroll
        for (int rg = 0; rg < 8; ++rg) {
            float v0 = mx[rg][0], v1 = mx[rg][1], v2 = mx[rg][2], v3 = mx[rg][3];
#pragma unroll
            for (int sh = 1; sh < 16; sh <<= 1) {
                v0 = fmaxf(v0, __shfl_xor(v0, sh, 64));
                v1 = fmaxf(v1, __shfl_xor(v1, sh, 64));
                v2 = fmaxf(v2, __shfl_xor(v2, sh, 64));
                v3 = fmaxf(v3, __shfl_xor(v3, sh, 64));
            }
            float vv = v0;
            vv = (col == 1) ? v1 : vv;
            vv = (col == 2) ? v2 : vv;
            vv = (col == 3) ? v3 : vv;
            if (ch == 0) {
                pmk[rg] = vv;            // defer: write both subs as float2
            } else if (col < 4) {
                f32x2 pr = {pmk[rg], vv};
                *reinterpret_cast<f32x2*>(
                    &pm[(size_t)(row0 + rg * 16 + kg * 4 + col) * NSUB + nr * 2]) = pr;
            }
            mx[rg][0] = -3.4e38f; mx[rg][1] = -3.4e38f;
            mx[rg][2] = -3.4e38f; mx[rg][3] = -3.4e38f;
        }

        if (WRITE_FINE) {   // 4x float4 per lane, fully coalesced
            const char* src = reinterpret_cast<const char*>(&fsh[wv][0]);
            char* dst = (char*)pmf + ((size_t)sub * 32 + rbk) * 4096;
#pragma unroll
            for (int i = 0; i < 4; ++i)
                *reinterpret_cast<float4*>(dst + i * 1024 + lane * 16) =
                    *reinterpret_cast<const float4*>(src + i * 1024 + lane * 16);
        }
    }
}

// ---- exact fp32 rescore + output (one wave per row) -----------------------
// sub -> base = sub*256; fine (sub,c): j = 0..15 -> n = base + j*16 + c
template <int FINE>
__global__ __launch_bounds__(256) void k_rescore(
        const float* __restrict__ x, const float* __restrict__ w,
        const float* __restrict__ w2c, const float* __restrict__ pm,
        const u16* __restrict__ pmf, float* __restrict__ out) {
    const int wv   = threadIdx.x >> 6;
    const int lane = threadIdx.x & 63;
    const int row  = blockIdx.x * 4 + wv;
    const int rbk2 = row >> 7;
    const int rl   = row & 127;

    float pv[4];
#pragma unroll
    for (int it = 0; it < 4; ++it)
        pv[it] = pm[(size_t)row * NSUB + it * 64 + lane];   // coalesced
    float gm = fmaxf(fmaxf(pv[0], pv[1]), fmaxf(pv[2], pv[3]));
#pragma unroll
    for (int s = 1; s < 64; s <<= 1) gm = fmaxf(gm, __shfl_xor(gm, s, 64));
    const float thr = gm - MARG_HALF;

    const float4* xr = reinterpret_cast<const float4*>(x + (size_t)row * D);
    float4 xq[16];
#pragma unroll
    for (int q = 0; q < 16; ++q) xq[q] = xr[q];

    float bestv = 3.4e38f;
    int   besti = 0x7fffffff;

#pragma unroll
    for (int it = 0; it < 4; ++it) {
        unsigned long long bm = __ballot(pv[it] >= thr);
        while (bm) {
            int sb = __ffsll(bm) - 1;
            bm &= bm - 1;
            int sub  = it * 64 + sb;
            int base = sub * 256;

            if (FINE) {
                // 16 fine bf16 (round-up) maxes, 32B coalesced
                float fv = -3.4e38f;
                if (lane < 16) {
                    union { unsigned u; float f; } c;
                    c.u = (unsigned)pmf[((size_t)sub * 32 + rbk2) * 2048
                                        + rl * 16 + lane] << 16;
                    fv = c.f;
                }
                unsigned long long fm = __ballot(fv >= thr);   // bits 0..15
                while (fm) {
                    int colq = __ffsll(fm) - 1;
                    fm &= fm - 1;
                    // fine sub n-set: base + j*16 + colq, j = 0..15
                    int j = lane & 15, q = lane >> 4;
                    int n = base + j * 16 + colq;
                    const float4* wr = reinterpret_cast<const float4*>(w + (size_t)n * D);
                    float d0 = 0.f, d1 = 0.f, d2 = 0.f, d3 = 0.f;
#pragma unroll
                    for (int k = 0; k < 4; ++k) {
                        float4 wq = wr[q * 4 + k];
                        float4 xv = xq[q * 4 + k];
                        d0 = fmaf(xv.x, wq.x, d0); d1 = fmaf(xv.y, wq.y, d1);
                        d2 = fmaf(xv.z, wq.z, d2); d3 = fmaf(xv.w, wq.w, d3);
                    }
                    float d = (d0 + d1) + (d2 + d3);
                    d += __shfl_xor(d, 16, 64);
                    d += __shfl_xor(d, 32, 64);      // all 4 copies hold full dot
                    float val = -2.f * (d + w2c[n]);  // == w2 - 2*x.w exact fp32
                    if (val < bestv || (val == bestv && n < besti)) { bestv = val; besti = n; }
                }
            } else {
#pragma unroll
                for (int p4 = 0; p4 < 4; ++p4) {
                    int n = base + p4 * 64 + lane;
                    const float4* wr = reinterpret_cast<const float4*>(w + (size_t)n * D);
                    float d0 = 0.f, d1 = 0.f, d2 = 0.f, d3 = 0.f;
#pragma unroll
                    for (int q = 0; q < 16; ++q) {
                        float4 wq = wr[q];
                        d0 = fmaf(xq[q].x, wq.x, d0);
                        d1 = fmaf(xq[q].y, wq.y, d1);
                        d2 = fmaf(xq[q].z, wq.z, d2);
                        d3 = fmaf(xq[q].w, wq.w, d3);
                    }
                    float dot = (d0 + d1) + (d2 + d3);
                    float val = -2.f * (dot + w2c[n]);
                    if (val < bestv || (val == bestv && n < besti)) { bestv = val; besti = n; }
                }
            }
        }
    }
#pragma unroll
    for (int s = 1; s < 64; s <<= 1) {
        float ov = __shfl_xor(bestv, s, 64);
        int   oi = __shfl_xor(besti, s, 64);
        if (ov < bestv || (ov == bestv && oi < besti)) { bestv = ov; besti = oi; }
    }
    if (lane == 0) {
        float a0 = 0.f, a1 = 0.f, a2 = 0.f, a3 = 0.f;
#pragma unroll
        for (int q = 0; q < 16; ++q) {
            a0 = fmaf(xq[q].x, xq[q].x, a0);
            a1 = fmaf(xq[q].y, xq[q].y, a1);
            a2 = fmaf(xq[q].z, xq[q].z, a2);
            a3 = fmaf(xq[q].w, xq[q].w, a3);
        }
        float x2 = (a0 + a1) + (a2 + a3);
        float d2f = x2 + bestv;
        if (d2f < 0.f) d2f = 0.f;
        out[row * 2 + 0] = (float)(besti >> 8);    // bmu_y
        out[row * 2 + 1] = (float)(besti & 255);   // bmu_x
        out[2 * B + row] = sqrtf(d2f);
    }
}

// ---- fallback (round-3 proven path, ~1.3 MB ws) ---------------------------
__global__ __launch_bounds__(256) void fb_w2(const float* __restrict__ w,
                                             float* __restrict__ w2) {
    int n = blockIdx.x * 256 + threadIdx.x;
    const float4* wr = reinterpret_cast<const float4*>(w + (size_t)n * D);
    float a0 = 0.f, a1 = 0.f, a2 = 0.f, a3 = 0.f;
#pragma unroll
    for (int q = 0; q < 16; ++q) {
        float4 v = wr[q];
        a0 = fmaf(v.x, v.x, a0); a1 = fmaf(v.y, v.y, a1);
        a2 = fmaf(v.z, v.z, a2); a3 = fmaf(v.w, v.w, a3);
    }
    w2[n] = (a0 + a1) + (a2 + a3);
}

__global__ __launch_bounds__(256) void fb_main(const float* __restrict__ x,
                                               const float* __restrict__ w,
                                               const float* __restrict__ w2,
                                               float* __restrict__ ps,
                                               int* __restrict__ pi) {
    constexpr int NSTRIP = NW / 32;
    const int rb    = blockIdx.x & 15;
    const int strip = blockIdx.x >> 4;
    const int row   = rb * 256 + threadIdx.x;
    float xr[D];
    const float4* xrow = reinterpret_cast<const float4*>(x + (size_t)row * D);
#pragma unroll
    for (int q = 0; q < 16; ++q) {
        float4 v = xrow[q];
        xr[q * 4 + 0] = v.x; xr[q * 4 + 1] = v.y;
        xr[q * 4 + 2] = v.z; xr[q * 4 + 3] = v.w;
    }
    float best = 3.4e38f; int bidx = 0;
    const int n0 = strip * NSTRIP, n1 = n0 + NSTRIP;
    for (int n = n0; n < n1; ++n) {
        const float* wr = w + (size_t)n * D;
        float a0 = 0.f, a1 = 0.f, a2 = 0.f, a3 = 0.f;
#pragma unroll
        for (int d = 0; d < D; d += 4) {
            a0 = fmaf(xr[d + 0], wr[d + 0], a0);
            a1 = fmaf(xr[d + 1], wr[d + 1], a1);
            a2 = fmaf(xr[d + 2], wr[d + 2], a2);
            a3 = fmaf(xr[d + 3], wr[d + 3], a3);
        }
        float s = fmaf(-2.f, (a0 + a1) + (a2 + a3), w2[n]);
        if (s < best) { best = s; bidx = n; }
    }
    ps[(size_t)strip * B + row] = best;
    pi[(size_t)strip * B + row] = bidx;
}

__global__ __launch_bounds__(256) void fb_merge(const float* __restrict__ x,
                                                const float* __restrict__ ps,
                                                const int* __restrict__ pi,
                                                float* __restrict__ out) {
    int row = blockIdx.x * 256 + threadIdx.x;
    float bs = 3.5e38f; int bi = 0;
    for (int t = 0; t < 32; ++t) {
        float s = ps[(size_t)t * B + row];
        int   i = pi[(size_t)t * B + row];
        if (s < bs || (s == bs && i < bi)) { bs = s; bi = i; }
    }
    const float4* xrow = reinterpret_cast<const float4*>(x + (size_t)row * D);
    float a0 = 0.f, a1 = 0.f, a2 = 0.f, a3 = 0.f;
#pragma unroll
    for (int q = 0; q < 16; ++q) {
        float4 v = xrow[q];
        a0 = fmaf(v.x, v.x, a0); a1 = fmaf(v.y, v.y, a1);
        a2 = fmaf(v.z, v.z, a2); a3 = fmaf(v.w, v.w, a3);
    }
    float x2 = (a0 + a1) + (a2 + a3);
    float d2 = x2 + bs;
    if (d2 < 0.f) d2 = 0.f;
    out[row * 2 + 0] = (float)(bi >> 8);
    out[row * 2 + 1] = (float)(bi & 255);
    out[2 * B + row] = sqrtf(d2);
}

// ---------------------------------------------------------------------------
extern "C" void kernel_launch(void* const* d_in, const int* in_sizes, int n_in,
                              void* d_out, int out_size, void* d_ws, size_t ws_size,
                              hipStream_t stream) {
    const float* x = (const float*)d_in[0];   // [B, D]
    const float* w = (const float*)d_in[1];   // [NW, D]
    float* out = (float*)d_out;

    const size_t whi_sz = (size_t)NW * D * 2;        // 8 MB
    const size_t xhi_sz = (size_t)B * D * 2;         // 512 KB
    const size_t w2c_sz = (size_t)NW * 4;            // 256 KB
    const size_t pm_sz  = (size_t)B * NSUB * 4;      // 4 MB
    const size_t pmf_sz = (size_t)NFINE * B * 2;     // 33.5 MB
    const size_t need_c = whi_sz + xhi_sz + w2c_sz + pm_sz;
    const size_t need_f = need_c + pmf_sz;

    if (ws_size >= need_c) {
        char* p = (char*)d_ws;
        u16*   whi = (u16*)p;   p += whi_sz;
        u16*   xhi = (u16*)p;   p += xhi_sz;
        float* w2c = (float*)p; p += w2c_sz;
        float* pm  = (float*)p; p += pm_sz;
        u16*   pmf = (u16*)p;

        k_prep<<<(2 * NW + 2 * B) / 256, 256, 0, stream>>>(w, x, whi, xhi, w2c);
        if (ws_size >= need_f) {
            k_screen0<1><<<NRANGE * RBKB, 256, 0, stream>>>(whi, xhi, w2c, pm, pmf);
            k_rescore<1><<<B / 4, 256, 0, stream>>>(x, w, w2c, pm, pmf, out);
        } else {
            k_screen0<0><<<NRANGE * RBKB, 256, 0, stream>>>(whi, xhi, w2c, pm, pmf);
            k_rescore<0><<<B / 4, 256, 0, stream>>>(x, w, w2c, pm, pmf, out);
        }
    } else {
        float* w2 = (float*)d_ws;
        float* ps = w2 + NW;
        int*   pi = (int*)(ps + (size_t)32 * B);
        fb_w2<<<NW / 256, 256, 0, stream>>>(w, w2);
        fb_main<<<16 * 32, 256, 0, stream>>>(x, w, w2, ps, pi);
        fb_merge<<<B / 256, 256, 0, stream>>>(x, ps, pi, out);
    }
}

// Round 22
// 108.983 us; speedup vs baseline: 1.0562x; 1.0236x over previous
//
#include <hip/hip_runtime.h>
#include <math.h>

// SOM2dLayer forward: BMU indices + quantization error.
// X[4096,64] f32, W[65536,64] f32 -> out f32: [B*2] (y,x) then [B] qe.
//
// acc'(row,n) = bf16dot(x,w) + w2c[n], w2c = -0.5*sum(w^2); s = -2*acc'.
// min_n s  <=>  max_n acc'.
//   k_prep:    r22 -- QUARTER-ROW prep (4 threads/row, shfl-combined w2
//              partials): r21's 2-way split gained 3.5us (prep was
//              latency-bound); 4-way halves the chain again, 1088 blocks.
//   k_screen0: r20 screen unchanged (depth-1-pair register prefetch, rg=8,
//              barrier-free, direct-global B, float2 pm writes).
//   k_rescore: unchanged (coalesced pv gather, fine bf16 localization,
//              exact fp32 rescore, first-index tie-break).
// Round-up bf16 pmf is conservative -> candidate superset, no false
// negatives. No atomics, no barriers -> deterministic.

typedef short  bf16x8 __attribute__((ext_vector_type(8)));
typedef float  f32x4  __attribute__((ext_vector_type(4)));
typedef float  f32x2  __attribute__((ext_vector_type(2)));
typedef unsigned short u16;

constexpr int D     = 64;
constexpr int NW    = 65536;
constexpr int B     = 4096;
constexpr int NSUB  = 256;             // coarse subs: 256 contiguous n each
constexpr int NFINE = NW / 16;         // 4096 fine subs (16 n each)
constexpr float MARG_HALF = 0.15f;     // bf16 screen margin (acc' scale)

constexpr int NRANGE = 128;            // n-ranges of 512 n (one per wave)
constexpr int RBKB   = 8;              // row-super-blocks (4 waves x 128 rows)

__device__ inline u16 bf16u(float f) {
    union { float f; unsigned u; } v; v.f = f;
    unsigned b = v.u;
    b += 0x7fffu + ((b >> 16) & 1u);   // RNE, finite inputs only
    return (u16)(b >> 16);
}

__device__ inline u16 bf16up(float f) {   // round toward +inf (conservative max)
    union { float f; unsigned u; } v; v.f = f;
    unsigned h = v.u >> 16;
    if ((v.u & 0xFFFFu) && !(v.u >> 31)) h += 1;
    return (u16)h;
}

// ---- prep: W,X -> bf16 + w2c (quarter-row: 4 threads per row) -------------
// Threads [0, 4*NW): W rows. Threads [4*NW, 4*NW+4*B): X rows.
// Thread t: row = t>>2, q4 = t&3 (elements q4*16 .. q4*16+16).
__global__ __launch_bounds__(256) void k_prep(const float* __restrict__ w,
                                              const float* __restrict__ x,
                                              u16* __restrict__ whi,
                                              u16* __restrict__ xhi,
                                              float* __restrict__ w2c) {
    const int t = blockIdx.x * 256 + threadIdx.x;
    if (t < 4 * NW) {
        const int row = t >> 2;
        const int q4  = t & 3;
        const float4* wr = reinterpret_cast<const float4*>(
            w + (size_t)row * D + q4 * 16);
        u16* orow = whi + (size_t)row * D + q4 * 16;
        float a0 = 0.f, a1 = 0.f, a2 = 0.f, a3 = 0.f;
#pragma unroll
        for (int h = 0; h < 2; ++h) {
            float4 v0 = wr[2 * h], v1 = wr[2 * h + 1];
            a0 = fmaf(v0.x, v0.x, a0); a1 = fmaf(v0.y, v0.y, a1);
            a2 = fmaf(v0.z, v0.z, a2); a3 = fmaf(v0.w, v0.w, a3);
            a0 = fmaf(v1.x, v1.x, a0); a1 = fmaf(v1.y, v1.y, a1);
            a2 = fmaf(v1.z, v1.z, a2); a3 = fmaf(v1.w, v1.w, a3);
            bf16x8 o = {(short)bf16u(v0.x), (short)bf16u(v0.y),
                        (short)bf16u(v0.z), (short)bf16u(v0.w),
                        (short)bf16u(v1.x), (short)bf16u(v1.y),
                        (short)bf16u(v1.z), (short)bf16u(v1.w)};
            *reinterpret_cast<bf16x8*>(orow + 8 * h) = o;
        }
        float p = (a0 + a1) + (a2 + a3);
        p += __shfl_xor(p, 1, 64);        // combine 4 quarter-partials
        p += __shfl_xor(p, 2, 64);
        if (q4 == 0) w2c[row] = -0.5f * p;
    } else {
        const int t2  = t - 4 * NW;
        const int row = t2 >> 2;
        const int q4  = t2 & 3;
        const float4* xr = reinterpret_cast<const float4*>(
            x + (size_t)row * D + q4 * 16);
        u16* orow = xhi + (size_t)row * D + q4 * 16;
#pragma unroll
        for (int h = 0; h < 2; ++h) {
            float4 v0 = xr[2 * h], v1 = xr[2 * h + 1];
            bf16x8 o = {(short)bf16u(v0.x), (short)bf16u(v0.y),
                        (short)bf16u(v0.z), (short)bf16u(v0.w),
                        (short)bf16u(v1.x), (short)bf16u(v1.y),
                        (short)bf16u(v1.z), (short)bf16u(v1.w)};
            *reinterpret_cast<bf16x8*>(orow + 8 * h) = o;
        }
    }
}

// ---- MFMA screen: rg=8, barrier-free, depth-1-pair register prefetch ------
// Block: 256 thr = 4 independent waves. nr = bid & 127; rbk = (bid>>7)*4+wv.
// Wave: rows [rbk*128, +128), n [nr*512, +512) = 16 tile-pairs (32 n each),
// 2 chunks of 256 n. XCD: bid%8 == nr%8.
// sub = nr*2 + ch (contiguous). fine (sub,col): n = sub*256 + j*16 + col.
// pm[row][sub] f32 (row-major, float2 per wave at ch=1);
// pmf[(sub*32+row>>7)*2048+(row&127)*16+col] u16 block-linear.
template <int WRITE_FINE>
__global__ __launch_bounds__(256, 2) void k_screen0(
        const u16* __restrict__ whi, const u16* __restrict__ xhi,
        const float* __restrict__ w2c, float* __restrict__ pm,
        u16* __restrict__ pmf) {
    __shared__ __align__(16) u16 fsh[4][2048];   // per-wave flush staging
    const int bid  = blockIdx.x;
    const int nr   = bid & (NRANGE - 1);
    const int tid  = threadIdx.x;
    const int wv   = tid >> 6;
    const int lane = tid & 63;
    const int col  = lane & 15;
    const int kg   = lane >> 4;
    const int rbk  = (bid >> 7) * 4 + wv;
    const int row0 = rbk * 128;
    const int W0   = nr * 512;

    // A fragments (x rows), resident whole kernel: 8 rg x 2 k-halves.
    bf16x8 a[8][2];
#pragma unroll
    for (int rg = 0; rg < 8; ++rg)
#pragma unroll
        for (int h = 0; h < 2; ++h)
            a[rg][h] = *reinterpret_cast<const bf16x8*>(
                xhi + (size_t)(row0 + rg * 16 + col) * D + h * 32 + kg * 8);

    float mx[8][4];
#pragma unroll
    for (int rg = 0; rg < 8; ++rg)
#pragma unroll
        for (int r = 0; r < 4; ++r) mx[rg][r] = -3.4e38f;

    float pmk[8];   // ch=0's folded pm values (valid in col<4 lanes)

    // pair-load into named registers (depth-1 prefetch sets)
    bf16x8 cb00, cb01, cb10, cb11, nb00, nb01, nb10, nb11;
    float  cc0, cc1, nc0, nc1;
    auto LDP = [&](int pp, bf16x8& b00, bf16x8& b01, bf16x8& b10, bf16x8& b11,
                   float& c0, float& c1) {
        const int n0 = W0 + pp * 32 + col;
        const int n1 = n0 + 16;
        const u16* p0 = whi + (size_t)n0 * D + kg * 8;
        const u16* p1 = whi + (size_t)n1 * D + kg * 8;
        b00 = *reinterpret_cast<const bf16x8*>(p0);
        b01 = *reinterpret_cast<const bf16x8*>(p0 + 32);
        b10 = *reinterpret_cast<const bf16x8*>(p1);
        b11 = *reinterpret_cast<const bf16x8*>(p1 + 32);
        c0 = w2c[n0];
        c1 = w2c[n1];
    };

    LDP(0, cb00, cb01, cb10, cb11, cc0, cc1);

    for (int ch = 0; ch < 2; ++ch) {
        for (int mp = 0; mp < 8; ++mp) {
            const int pp = ch * 8 + mp;
            // issue NEXT pair's loads before current pair's compute
            if (pp + 1 < 16)
                LDP(pp + 1, nb00, nb01, nb10, nb11, nc0, nc1);

            const f32x4 cq0 = {cc0, cc0, cc0, cc0};
            const f32x4 cq1 = {cc1, cc1, cc1, cc1};
#pragma unroll
            for (int rg = 0; rg < 8; ++rg) {
                f32x4 acc = __builtin_amdgcn_mfma_f32_16x16x32_bf16(a[rg][0], cb00, cq0, 0, 0, 0);
                acc = __builtin_amdgcn_mfma_f32_16x16x32_bf16(a[rg][1], cb01, acc, 0, 0, 0);
                mx[rg][0] = fmaxf(mx[rg][0], acc[0]);
                mx[rg][1] = fmaxf(mx[rg][1], acc[1]);
                mx[rg][2] = fmaxf(mx[rg][2], acc[2]);
                mx[rg][3] = fmaxf(mx[rg][3], acc[3]);
            }
#pragma unroll
            for (int rg = 0; rg < 8; ++rg) {
                f32x4 acc = __builtin_amdgcn_mfma_f32_16x16x32_bf16(a[rg][0], cb10, cq1, 0, 0, 0);
                acc = __builtin_amdgcn_mfma_f32_16x16x32_bf16(a[rg][1], cb11, acc, 0, 0, 0);
                mx[rg][0] = fmaxf(mx[rg][0], acc[0]);
                mx[rg][1] = fmaxf(mx[rg][1], acc[1]);
                mx[rg][2] = fmaxf(mx[rg][2], acc[2]);
                mx[rg][3] = fmaxf(mx[rg][3], acc[3]);
            }
            cb00 = nb00; cb01 = nb01; cb10 = nb10; cb11 = nb11;
            cc0 = nc0;   cc1 = nc1;
        }

        // ---- chunk flush (2 per kernel, wave-private, no barriers) ----
        const int sub = nr * 2 + ch;

        if (WRITE_FINE) {   // transpose deposit -> coalesced writeout
#pragma unroll
            for (int rg = 0; rg < 8; ++rg)
#pragma unroll
                for (int r = 0; r < 4; ++r)
                    fsh[wv][(rg * 16 + kg * 4 + r) * 16 + col] = bf16up(mx[rg][r]);
        }

#pragma unroll
        for (int rg = 0; rg < 8; ++rg) {
            float v0 = mx[rg][0], v1 = mx[rg][1], v2 = mx[rg][2], v3 = mx[rg][3];
#pragma unroll
            for (int sh = 1; sh < 16; sh <<= 1) {
                v0 = fmaxf(v0, __shfl_xor(v0, sh, 64));
                v1 = fmaxf(v1, __shfl_xor(v1, sh, 64));
                v2 = fmaxf(v2, __shfl_xor(v2, sh, 64));
                v3 = fmaxf(v3, __shfl_xor(v3, sh, 64));
            }
            float vv = v0;
            vv = (col == 1) ? v1 : vv;
            vv = (col == 2) ? v2 : vv;
            vv = (col == 3) ? v3 : vv;
            if (ch == 0) {
                pmk[rg] = vv;            // defer: write both subs as float2
            } else if (col < 4) {
                f32x2 pr = {pmk[rg], vv};
                *reinterpret_cast<f32x2*>(
                    &pm[(size_t)(row0 + rg * 16 + kg * 4 + col) * NSUB + nr * 2]) = pr;
            }
            mx[rg][0] = -3.4e38f; mx[rg][1] = -3.4e38f;
            mx[rg][2] = -3.4e38f; mx[rg][3] = -3.4e38f;
        }

        if (WRITE_FINE) {   // 4x float4 per lane, fully coalesced
            const char* src = reinterpret_cast<const char*>(&fsh[wv][0]);
            char* dst = (char*)pmf + ((size_t)sub * 32 + rbk) * 4096;
#pragma unroll
            for (int i = 0; i < 4; ++i)
                *reinterpret_cast<float4*>(dst + i * 1024 + lane * 16) =
                    *reinterpret_cast<const float4*>(src + i * 1024 + lane * 16);
        }
    }
}

// ---- exact fp32 rescore + output (one wave per row) -----------------------
// sub -> base = sub*256; fine (sub,c): j = 0..15 -> n = base + j*16 + c
template <int FINE>
__global__ __launch_bounds__(256) void k_rescore(
        const float* __restrict__ x, const float* __restrict__ w,
        const float* __restrict__ w2c, const float* __restrict__ pm,
        const u16* __restrict__ pmf, float* __restrict__ out) {
    const int wv   = threadIdx.x >> 6;
    const int lane = threadIdx.x & 63;
    const int row  = blockIdx.x * 4 + wv;
    const int rbk2 = row >> 7;
    const int rl   = row & 127;

    float pv[4];
#pragma unroll
    for (int it = 0; it < 4; ++it)
        pv[it] = pm[(size_t)row * NSUB + it * 64 + lane];   // coalesced
    float gm = fmaxf(fmaxf(pv[0], pv[1]), fmaxf(pv[2], pv[3]));
#pragma unroll
    for (int s = 1; s < 64; s <<= 1) gm = fmaxf(gm, __shfl_xor(gm, s, 64));
    const float thr = gm - MARG_HALF;

    const float4* xr = reinterpret_cast<const float4*>(x + (size_t)row * D);
    float4 xq[16];
#pragma unroll
    for (int q = 0; q < 16; ++q) xq[q] = xr[q];

    float bestv = 3.4e38f;
    int   besti = 0x7fffffff;

#pragma unroll
    for (int it = 0; it < 4; ++it) {
        unsigned long long bm = __ballot(pv[it] >= thr);
        while (bm) {
            int sb = __ffsll(bm) - 1;
            bm &= bm - 1;
            int sub  = it * 64 + sb;
            int base = sub * 256;

            if (FINE) {
                // 16 fine bf16 (round-up) maxes, 32B coalesced
                float fv = -3.4e38f;
                if (lane < 16) {
                    union { unsigned u; float f; } c;
                    c.u = (unsigned)pmf[((size_t)sub * 32 + rbk2) * 2048
                                        + rl * 16 + lane] << 16;
                    fv = c.f;
                }
                unsigned long long fm = __ballot(fv >= thr);   // bits 0..15
                while (fm) {
                    int colq = __ffsll(fm) - 1;
                    fm &= fm - 1;
                    // fine sub n-set: base + j*16 + colq, j = 0..15
                    int j = lane & 15, q = lane >> 4;
                    int n = base + j * 16 + colq;
                    const float4* wr = reinterpret_cast<const float4*>(w + (size_t)n * D);
                    float d0 = 0.f, d1 = 0.f, d2 = 0.f, d3 = 0.f;
#pragma unroll
                    for (int k = 0; k < 4; ++k) {
                        float4 wq = wr[q * 4 + k];
                        float4 xv = xq[q * 4 + k];
                        d0 = fmaf(xv.x, wq.x, d0); d1 = fmaf(xv.y, wq.y, d1);
                        d2 = fmaf(xv.z, wq.z, d2); d3 = fmaf(xv.w, wq.w, d3);
                    }
                    float d = (d0 + d1) + (d2 + d3);
                    d += __shfl_xor(d, 16, 64);
                    d += __shfl_xor(d, 32, 64);      // all 4 copies hold full dot
                    float val = -2.f * (d + w2c[n]);  // == w2 - 2*x.w exact fp32
                    if (val < bestv || (val == bestv && n < besti)) { bestv = val; besti = n; }
                }
            } else {
#pragma unroll
                for (int p4 = 0; p4 < 4; ++p4) {
                    int n = base + p4 * 64 + lane;
                    const float4* wr = reinterpret_cast<const float4*>(w + (size_t)n * D);
                    float d0 = 0.f, d1 = 0.f, d2 = 0.f, d3 = 0.f;
#pragma unroll
                    for (int q = 0; q < 16; ++q) {
                        float4 wq = wr[q];
                        d0 = fmaf(xq[q].x, wq.x, d0);
                        d1 = fmaf(xq[q].y, wq.y, d1);
                        d2 = fmaf(xq[q].z, wq.z, d2);
                        d3 = fmaf(xq[q].w, wq.w, d3);
                    }
                    float dot = (d0 + d1) + (d2 + d3);
                    float val = -2.f * (dot + w2c[n]);
                    if (val < bestv || (val == bestv && n < besti)) { bestv = val; besti = n; }
                }
            }
        }
    }
#pragma unroll
    for (int s = 1; s < 64; s <<= 1) {
        float ov = __shfl_xor(bestv, s, 64);
        int   oi = __shfl_xor(besti, s, 64);
        if (ov < bestv || (ov == bestv && oi < besti)) { bestv = ov; besti = oi; }
    }
    if (lane == 0) {
        float a0 = 0.f, a1 = 0.f, a2 = 0.f, a3 = 0.f;
#pragma unroll
        for (int q = 0; q < 16; ++q) {
            a0 = fmaf(xq[q].x, xq[q].x, a0);
            a1 = fmaf(xq[q].y, xq[q].y, a1);
            a2 = fmaf(xq[q].z, xq[q].z, a2);
            a3 = fmaf(xq[q].w, xq[q].w, a3);
        }
        float x2 = (a0 + a1) + (a2 + a3);
        float d2f = x2 + bestv;
        if (d2f < 0.f) d2f = 0.f;
        out[row * 2 + 0] = (float)(besti >> 8);    // bmu_y
        out[row * 2 + 1] = (float)(besti & 255);   // bmu_x
        out[2 * B + row] = sqrtf(d2f);
    }
}

// ---- fallback (round-3 proven path, ~1.3 MB ws) ---------------------------
__global__ __launch_bounds__(256) void fb_w2(const float* __restrict__ w,
                                             float* __restrict__ w2) {
    int n = blockIdx.x * 256 + threadIdx.x;
    const float4* wr = reinterpret_cast<const float4*>(w + (size_t)n * D);
    float a0 = 0.f, a1 = 0.f, a2 = 0.f, a3 = 0.f;
#pragma unroll
    for (int q = 0; q < 16; ++q) {
        float4 v = wr[q];
        a0 = fmaf(v.x, v.x, a0); a1 = fmaf(v.y, v.y, a1);
        a2 = fmaf(v.z, v.z, a2); a3 = fmaf(v.w, v.w, a3);
    }
    w2[n] = (a0 + a1) + (a2 + a3);
}

__global__ __launch_bounds__(256) void fb_main(const float* __restrict__ x,
                                               const float* __restrict__ w,
                                               const float* __restrict__ w2,
                                               float* __restrict__ ps,
                                               int* __restrict__ pi) {
    constexpr int NSTRIP = NW / 32;
    const int rb    = blockIdx.x & 15;
    const int strip = blockIdx.x >> 4;
    const int row   = rb * 256 + threadIdx.x;
    float xr[D];
    const float4* xrow = reinterpret_cast<const float4*>(x + (size_t)row * D);
#pragma unroll
    for (int q = 0; q < 16; ++q) {
        float4 v = xrow[q];
        xr[q * 4 + 0] = v.x; xr[q * 4 + 1] = v.y;
        xr[q * 4 + 2] = v.z; xr[q * 4 + 3] = v.w;
    }
    float best = 3.4e38f; int bidx = 0;
    const int n0 = strip * NSTRIP, n1 = n0 + NSTRIP;
    for (int n = n0; n < n1; ++n) {
        const float* wr = w + (size_t)n * D;
        float a0 = 0.f, a1 = 0.f, a2 = 0.f, a3 = 0.f;
#pragma unroll
        for (int d = 0; d < D; d += 4) {
            a0 = fmaf(xr[d + 0], wr[d + 0], a0);
            a1 = fmaf(xr[d + 1], wr[d + 1], a1);
            a2 = fmaf(xr[d + 2], wr[d + 2], a2);
            a3 = fmaf(xr[d + 3], wr[d + 3], a3);
        }
        float s = fmaf(-2.f, (a0 + a1) + (a2 + a3), w2[n]);
        if (s < best) { best = s; bidx = n; }
    }
    ps[(size_t)strip * B + row] = best;
    pi[(size_t)strip * B + row] = bidx;
}

__global__ __launch_bounds__(256) void fb_merge(const float* __restrict__ x,
                                                const float* __restrict__ ps,
                                                const int* __restrict__ pi,
                                                float* __restrict__ out) {
    int row = blockIdx.x * 256 + threadIdx.x;
    float bs = 3.5e38f; int bi = 0;
    for (int t = 0; t < 32; ++t) {
        float s = ps[(size_t)t * B + row];
        int   i = pi[(size_t)t * B + row];
        if (s < bs || (s == bs && i < bi)) { bs = s; bi = i; }
    }
    const float4* xrow = reinterpret_cast<const float4*>(x + (size_t)row * D);
    float a0 = 0.f, a1 = 0.f, a2 = 0.f, a3 = 0.f;
#pragma unroll
    for (int q = 0; q < 16; ++q) {
        float4 v = xrow[q];
        a0 = fmaf(v.x, v.x, a0); a1 = fmaf(v.y, v.y, a1);
        a2 = fmaf(v.z, v.z, a2); a3 = fmaf(v.w, v.w, a3);
    }
    float x2 = (a0 + a1) + (a2 + a3);
    float d2 = x2 + bs;
    if (d2 < 0.f) d2 = 0.f;
    out[row * 2 + 0] = (float)(bi >> 8);
    out[row * 2 + 1] = (float)(bi & 255);
    out[2 * B + row] = sqrtf(d2);
}

// ---------------------------------------------------------------------------
extern "C" void kernel_launch(void* const* d_in, const int* in_sizes, int n_in,
                              void* d_out, int out_size, void* d_ws, size_t ws_size,
                              hipStream_t stream) {
    const float* x = (const float*)d_in[0];   // [B, D]
    const float* w = (const float*)d_in[1];   // [NW, D]
    float* out = (float*)d_out;

    const size_t whi_sz = (size_t)NW * D * 2;        // 8 MB
    const size_t xhi_sz = (size_t)B * D * 2;         // 512 KB
    const size_t w2c_sz = (size_t)NW * 4;            // 256 KB
    const size_t pm_sz  = (size_t)B * NSUB * 4;      // 4 MB
    const size_t pmf_sz = (size_t)NFINE * B * 2;     // 33.5 MB
    const size_t need_c = whi_sz + xhi_sz + w2c_sz + pm_sz;
    const size_t need_f = need_c + pmf_sz;

    if (ws_size >= need_c) {
        char* p = (char*)d_ws;
        u16*   whi = (u16*)p;   p += whi_sz;
        u16*   xhi = (u16*)p;   p += xhi_sz;
        float* w2c = (float*)p; p += w2c_sz;
        float* pm  = (float*)p; p += pm_sz;
        u16*   pmf = (u16*)p;

        k_prep<<<(4 * NW + 4 * B) / 256, 256, 0, stream>>>(w, x, whi, xhi, w2c);
        if (ws_size >= need_f) {
            k_screen0<1><<<NRANGE * RBKB, 256, 0, stream>>>(whi, xhi, w2c, pm, pmf);
            k_rescore<1><<<B / 4, 256, 0, stream>>>(x, w, w2c, pm, pmf, out);
        } else {
            k_screen0<0><<<NRANGE * RBKB, 256, 0, stream>>>(whi, xhi, w2c, pm, pmf);
            k_rescore<0><<<B / 4, 256, 0, stream>>>(x, w, w2c, pm, pmf, out);
        }
    } else {
        float* w2 = (float*)d_ws;
        float* ps = w2 + NW;
        int*   pi = (int*)(ps + (size_t)32 * B);
        fb_w2<<<NW / 256, 256, 0, stream>>>(w, w2);
        fb_main<<<16 * 32, 256, 0, stream>>>(x, w, w2, ps, pi);
        fb_merge<<<B / 256, 256, 0, stream>>>(x, ps, pi, out);
    }
}